// Round 8
// baseline (43.263 us; speedup 1.0000x reference)
//
#include <hip/hip_runtime.h>

#define N_NODES 207
#define N_EDGES 1722
#define N_SLOTS 288
#define L_DIM 24            // 2*12 feature channels
#define HCH 12              // channels per half-block (channel-split x2)
#define TOT_ENT (2 * N_EDGES)   // 3444
#define WTP 3456                // padded entry count (uint4-friendly)

typedef float f32x2 __attribute__((ext_vector_type(2)));
typedef __fp16 h16x2 __attribute__((ext_vector_type(2)));

// pack 2 f32 -> f16x2 (v_cvt_pkrtz_f16_f32)
__device__ __forceinline__ unsigned pkrtz(float a, float b) {
    h16x2 h = __builtin_amdgcn_cvt_pkrtz(a, b);
    return __builtin_bit_cast(unsigned, h);
}
__device__ __forceinline__ f32x2 h2f(unsigned u) {
    h16x2 h = __builtin_bit_cast(h16x2, u);
    f32x2 r; r.x = (float)h.x; r.y = (float)h.y;
    return r;
}
// acc(f16x2) += {wr,wr} * x ; wr = lo16 of wt. op_sel broadcasts lo half.
__device__ __forceinline__ void fma_lo(unsigned& acc, unsigned wt, unsigned x) {
    asm("v_pk_fma_f16 %0, %1, %2, %0 op_sel:[0,0,0] op_sel_hi:[0,1,1]"
        : "+v"(acc) : "v"(wt), "v"(x));
}
// acc(f16x2) += {wd,wd} * x ; wd = hi16 of wt.
__device__ __forceinline__ void fma_hi(unsigned& acc, unsigned wt, unsigned x) {
    asm("v_pk_fma_f16 %0, %1, %2, %0 op_sel:[1,0,0] op_sel_hi:[1,1,1]"
        : "+v"(acc) : "v"(wt), "v"(x));
}
// sw(f16x2) += {wr,wd}  (degree sums for both matrices in one op)
__device__ __forceinline__ void addw(unsigned& sw, unsigned wt) {
    asm("v_pk_add_f16 %0, %1, %0" : "+v"(sw) : "v"(wt));
}
// fast tanh: 1 - 2/(e^{2x}+1); both saturation limits exact.
__device__ __forceinline__ float fast_tanhf(float x) {
    float e2 = __expf(2.0f * x);
    return 1.0f - 2.0f * __builtin_amdgcn_rcpf(e2 + 1.0f);
}

// ---------------------------------------------------------------------------
// Kernel 1 (1 block): CSR incidence + degree-desc perm. Writes per-entry
// edge ids (for wperm) and u8 neighbor ids (for main).
// ---------------------------------------------------------------------------
__global__ __launch_bounds__(256) void build_csr_kernel(
    const int* __restrict__ edge_index,     // [2, N_EDGES]
    int* __restrict__ csr_off,              // [N_NODES + 1]
    int* __restrict__ perm,                 // [N_NODES] degree-desc order
    unsigned* __restrict__ ent_edge,        // [WTP] edge id per entry
    unsigned char* __restrict__ nbr_g)      // [WTP] neighbor per entry
{
    __shared__ int cnt[N_NODES];
    __shared__ int cursor[N_NODES];
    __shared__ int wsum[4];
    __shared__ int dcur[64];
    const int tid  = threadIdx.x;
    const int lane = tid & 63;
    const int wid  = tid >> 6;

    if (tid < N_NODES) cnt[tid] = 0;
    if (tid < 64) dcur[tid] = 0;
    __syncthreads();

    for (int e = tid; e < N_EDGES; e += 256) {
        int i = edge_index[e];
        int j = edge_index[N_EDGES + e];
        atomicAdd(&cnt[i], 1);
        atomicAdd(&cnt[j], 1);
    }
    __syncthreads();

    const int deg = (tid < N_NODES) ? cnt[tid] : 0;
    int x = deg;
    #pragma unroll
    for (int s = 1; s < 64; s <<= 1) {
        int t = __shfl_up(x, s, 64);
        if (lane >= s) x += t;
    }
    if (lane == 63) wsum[wid] = x;
    int dcap = deg > 63 ? 63 : deg;
    if (tid < N_NODES) atomicAdd(&dcur[dcap], 1);
    __syncthreads();

    int base = 0;
    for (int i = 0; i < wid; ++i) base += wsum[i];
    const int excl = base + x - deg;
    if (tid < N_NODES) { csr_off[tid] = excl; cursor[tid] = excl; }
    if (tid == 255)    { csr_off[N_NODES] = base + x; }

    if (tid < 64) {
        int h = dcur[63 - tid];
        int xs = h;
        #pragma unroll
        for (int s = 1; s < 64; s <<= 1) {
            int t = __shfl_up(xs, s, 64);
            if (lane >= s) xs += t;
        }
        __syncthreads();
        dcur[63 - tid] = xs - h;
    } else {
        __syncthreads();
    }
    __syncthreads();

    if (tid < N_NODES) {
        int p = atomicAdd(&dcur[dcap], 1);
        perm[p] = tid;
    }
    __syncthreads();

    for (int e = tid; e < N_EDGES; e += 256) {
        int i = edge_index[e];
        int j = edge_index[N_EDGES + e];
        int pi = atomicAdd(&cursor[i], 1);
        ent_edge[pi] = (unsigned)e;
        nbr_g[pi] = (unsigned char)j;
        int pj = atomicAdd(&cursor[j], 1);
        ent_edge[pj] = (unsigned)e;
        nbr_g[pj] = (unsigned char)i;
    }
}

// ---------------------------------------------------------------------------
// Kernel 2 (288 blocks): per-slot entry-ordered packed f16x2 weights.
// wtp[s][k] = pack(wr[s, edge(k)], wd[s, edge(k)]) — removes the edge-id
// indirection from the main loop and the per-block packing work.
// ---------------------------------------------------------------------------
__global__ __launch_bounds__(256) void wperm_kernel(
    const unsigned* __restrict__ ent_edge,
    const float* __restrict__ w_react,
    const float* __restrict__ w_diff,
    unsigned* __restrict__ wtp)             // [N_SLOTS, WTP]
{
    const int s = blockIdx.x;
    const float* wrg = w_react + (size_t)s * N_EDGES;
    const float* wdg = w_diff  + (size_t)s * N_EDGES;
    unsigned* o = wtp + (size_t)s * WTP;
    for (int k = threadIdx.x; k < TOT_ENT; k += 256) {
        unsigned e = ent_edge[k];
        o[k] = pkrtz(wrg[e], wdg[e]);
    }
}

// ---------------------------------------------------------------------------
// Kernel 3 (2048 blocks): fused main. Block = (sample b, channel-half cid);
// cid = bid>>10 so (b,0),(b,1) land on the same XCD (1024 % 8 == 0) and
// share x reads in L2. Thread tid owns node perm[tid] for 12 channels.
// LDS 22.3 KB -> 6 blocks/CU (24 waves) vs 4-block grid cap before.
// Loop body: 1 u8 + 1 b32 + 3 b64 LDS, 12 v_pk_fma_f16 (op_sel broadcast),
// 1 v_pk_add_f16 — no unpack, no splat, no indirection.
// ---------------------------------------------------------------------------
__global__ __launch_bounds__(256, 6) void rdgcn_main_kernel(
    const float* __restrict__ x_in,      // [B, 24, 207]
    const float* __restrict__ b_react,   // [N_SLOTS, N_NODES]
    const float* __restrict__ b_diff,    // [N_SLOTS, N_NODES]
    const float* __restrict__ w_self,    // [N_SLOTS, N_NODES]
    const int* __restrict__ ind,         // [B]
    const int* __restrict__ csr_off,     // [N_NODES + 1]
    const int* __restrict__ perm,        // [N_NODES]
    const unsigned char* __restrict__ nbr_g, // [WTP]
    const unsigned* __restrict__ wtp,    // [N_SLOTS, WTP]
    float* __restrict__ out)             // [B, 207, 24]
{
    __shared__ unsigned x_sh[N_NODES * 6];      // f16x2 half-rows, 24 B each
    __shared__ unsigned wt_sh[WTP];             // 13824 B
    __shared__ unsigned char nbr_sh[WTP];       // 3456 B   (total 22248 B)

    const int bid = blockIdx.x;
    const int b   = bid & 1023;
    const int cid = bid >> 10;          // channel half
    const int tid = threadIdx.x;
    const int s   = ind[b];             // RESOLUTION == 1

    // Hoist per-thread scalars; latency hides under staging.
    int w = 0, beg = 0, end = 0;
    float br = 0.f, bd = 0.f, wsl = 0.f;
    if (tid < N_NODES) {
        w   = perm[tid];
        beg = csr_off[w];
        end = csr_off[w + 1];
        br  = b_react[s * N_NODES + w];
        bd  = b_diff [s * N_NODES + w];
        wsl = w_self [s * N_NODES + w];
    }

    // Stage packed weights (864 uint4) and neighbors (216 uint4).
    {
        const uint4* g = reinterpret_cast<const uint4*>(wtp + (size_t)s * WTP);
        uint4* d = reinterpret_cast<uint4*>(wt_sh);
        for (int k = tid; k < WTP / 4; k += 256) d[k] = g[k];
    }
    {
        const uint4* g = reinterpret_cast<const uint4*>(nbr_g);
        uint4* d = reinterpret_cast<uint4*>(nbr_sh);
        if (tid < WTP / 16) d[tid] = g[tid];
    }
    // Stage this half's x channels: 12 coalesced loads -> 6 f16x2 words.
    const float* xg = x_in + (size_t)b * (L_DIM * N_NODES) + cid * (HCH * N_NODES);
    if (tid < N_NODES) {
        float r[HCH];
        #pragma unroll
        for (int l = 0; l < HCH; ++l) r[l] = xg[l * N_NODES + tid];
        unsigned p[6];
        #pragma unroll
        for (int i = 0; i < 6; ++i) p[i] = pkrtz(r[2*i], r[2*i+1]);
        uint2* dst = reinterpret_cast<uint2*>(&x_sh[tid * 6]);
        dst[0] = make_uint2(p[0], p[1]);
        dst[1] = make_uint2(p[2], p[3]);
        dst[2] = make_uint2(p[4], p[5]);
    }
    __syncthreads();

    if (tid >= N_NODES) return;

    unsigned accr[6] = {0,0,0,0,0,0};   // f16x2 accumulators (reaction)
    unsigned accd[6] = {0,0,0,0,0,0};   // f16x2 accumulators (diffusion)
    unsigned sw = 0;                    // f16x2 (d_r, d_d) degree sums

    for (int k = beg; k < end; ++k) {
        const int nbr = nbr_sh[k];
        const unsigned wt = wt_sh[k];
        const uint2* xr = reinterpret_cast<const uint2*>(&x_sh[nbr * 6]);
        const uint2 a = xr[0], bq = xr[1], c = xr[2];
        addw(sw, wt);
        fma_lo(accr[0], wt, a.x);   fma_hi(accd[0], wt, a.x);
        fma_lo(accr[1], wt, a.y);   fma_hi(accd[1], wt, a.y);
        fma_lo(accr[2], wt, bq.x);  fma_hi(accd[2], wt, bq.x);
        fma_lo(accr[3], wt, bq.y);  fma_hi(accd[3], wt, bq.y);
        fma_lo(accr[4], wt, c.x);   fma_hi(accd[4], wt, c.x);
        fma_lo(accr[5], wt, c.y);   fma_hi(accd[5], wt, c.y);
    }

    const f32x2 sw2 = h2f(sw);
    const float swr = sw2.x, swd = sw2.y;

    const uint2* xw = reinterpret_cast<const uint2*>(&x_sh[w * 6]);
    const uint2 o0w = xw[0], o1w = xw[1], o2w = xw[2];
    const unsigned own[6] = { o0w.x, o0w.y, o1w.x, o1w.y, o2w.x, o2w.y };

    float o[HCH];
    #pragma unroll
    for (int i = 0; i < 6; ++i) {
        const f32x2 xv = h2f(own[i]);
        const f32x2 ar = h2f(accr[i]);
        const f32x2 ad = h2f(accd[i]);
        {
            float re = fmaf(swr, xv.x,  ar.x) + br;
            float di = fmaf(swd, xv.x, -ad.x) + bd;
            o[2*i]   = fast_tanhf(re) + di + fmaf(xv.x, wsl, xv.x);
        }
        {
            float re = fmaf(swr, xv.y,  ar.y) + br;
            float di = fmaf(swd, xv.y, -ad.y) + bd;
            o[2*i+1] = fast_tanhf(re) + di + fmaf(xv.y, wsl, xv.y);
        }
    }
    float* op = out + (size_t)b * (N_NODES * L_DIM) + (size_t)w * L_DIM + cid * HCH;
    reinterpret_cast<float4*>(op)[0] = make_float4(o[0], o[1], o[2],  o[3]);
    reinterpret_cast<float4*>(op)[1] = make_float4(o[4], o[5], o[6],  o[7]);
    reinterpret_cast<float4*>(op)[2] = make_float4(o[8], o[9], o[10], o[11]);
}

extern "C" void kernel_launch(void* const* d_in, const int* in_sizes, int n_in,
                              void* d_out, int out_size, void* d_ws, size_t ws_size,
                              hipStream_t stream) {
    const float* x_in     = (const float*)d_in[0];
    const float* w_react  = (const float*)d_in[1];
    const float* w_diff   = (const float*)d_in[2];
    const float* b_react  = (const float*)d_in[3];
    const float* b_diff   = (const float*)d_in[4];
    const float* w_self   = (const float*)d_in[5];
    const int*   ind      = (const int*)d_in[6];
    const int*   edge_idx = (const int*)d_in[7];
    float* out = (float*)d_out;

    // ws: csr_off | perm | ent_edge | nbr | wtp (288 x 3456 u32 = 3.98 MB)
    char* wp = (char*)d_ws;
    int* csr_off = (int*)wp;                 wp += 1024;
    int* perm = (int*)wp;                    wp += 1024;
    unsigned* ent_edge = (unsigned*)wp;      wp += WTP * sizeof(unsigned);
    unsigned char* nbr_g = (unsigned char*)wp; wp += (WTP + 256);
    wp = (char*)(((size_t)wp + 255) & ~(size_t)255);
    unsigned* wtp = (unsigned*)wp;

    build_csr_kernel<<<1, 256, 0, stream>>>(edge_idx, csr_off, perm,
                                            ent_edge, nbr_g);
    wperm_kernel<<<N_SLOTS, 256, 0, stream>>>(ent_edge, w_react, w_diff, wtp);

    const int B = in_sizes[6];   // 1024
    rdgcn_main_kernel<<<2 * B, 256, 0, stream>>>(x_in, b_react, b_diff, w_self,
                                                 ind, csr_off, perm, nbr_g,
                                                 wtp, out);
}

// Round 10
// 38.511 us; speedup vs baseline: 1.1234x; 1.1234x over previous
//
#include <hip/hip_runtime.h>

#define N_NODES 207
#define N_EDGES 1722
#define N_SLOTS 288
#define L_DIM 24            // 2*12 feature channels
#define NPK 12              // f16x2 words per node row (24 ch, 48 B)
#define TOT_ENT (2 * N_EDGES)   // 3444
#define WTP 3456                // padded entry count (uint4-friendly)

typedef float f32x2 __attribute__((ext_vector_type(2)));
typedef __fp16 h16x2 __attribute__((ext_vector_type(2)));

// pack 2 f32 -> f16x2 (v_cvt_pkrtz_f16_f32)
__device__ __forceinline__ unsigned pkrtz(float a, float b) {
    h16x2 h = __builtin_amdgcn_cvt_pkrtz(a, b);
    return __builtin_bit_cast(unsigned, h);
}
__device__ __forceinline__ f32x2 h2f(unsigned u) {
    h16x2 h = __builtin_bit_cast(h16x2, u);
    f32x2 r; r.x = (float)h.x; r.y = (float)h.y;
    return r;
}
// acc(f16x2) += {wr,wr} * x ; wr = lo16 of wt (op_sel lo-broadcast).
__device__ __forceinline__ void fma_lo(unsigned& acc, unsigned wt, unsigned x) {
    asm("v_pk_fma_f16 %0, %1, %2, %0 op_sel:[0,0,0] op_sel_hi:[0,1,1]"
        : "+v"(acc) : "v"(wt), "v"(x));
}
// acc(f16x2) += {wd,wd} * x ; wd = hi16 of wt.
__device__ __forceinline__ void fma_hi(unsigned& acc, unsigned wt, unsigned x) {
    asm("v_pk_fma_f16 %0, %1, %2, %0 op_sel:[1,0,0] op_sel_hi:[1,1,1]"
        : "+v"(acc) : "v"(wt), "v"(x));
}
// sw(f16x2) += {wr,wd}  (degree sums for both matrices in one op)
__device__ __forceinline__ void addw(unsigned& sw, unsigned wt) {
    asm("v_pk_add_f16 %0, %1, %0" : "+v"(sw) : "v"(wt));
}
// fast tanh: 1 - 2/(e^{2x}+1); both saturation limits exact.
__device__ __forceinline__ float fast_tanhf(float x) {
    float e2 = __expf(2.0f * x);
    return 1.0f - 2.0f * __builtin_amdgcn_rcpf(e2 + 1.0f);
}

// ---------------------------------------------------------------------------
// Kernel 1 (1 block): CSR incidence + degree-desc perm. Writes per-entry
// edge ids (for wperm) and u8 neighbor ids (for main).
// ---------------------------------------------------------------------------
__global__ __launch_bounds__(256) void build_csr_kernel(
    const int* __restrict__ edge_index,     // [2, N_EDGES]
    int* __restrict__ csr_off,              // [N_NODES + 1]
    int* __restrict__ perm,                 // [N_NODES] degree-desc order
    unsigned* __restrict__ ent_edge,        // [WTP] edge id per entry
    unsigned char* __restrict__ nbr_g)      // [WTP] neighbor per entry
{
    __shared__ int cnt[N_NODES];
    __shared__ int cursor[N_NODES];
    __shared__ int wsum[4];
    __shared__ int dcur[64];
    const int tid  = threadIdx.x;
    const int lane = tid & 63;
    const int wid  = tid >> 6;

    if (tid < N_NODES) cnt[tid] = 0;
    if (tid < 64) dcur[tid] = 0;
    __syncthreads();

    for (int e = tid; e < N_EDGES; e += 256) {
        int i = edge_index[e];
        int j = edge_index[N_EDGES + e];
        atomicAdd(&cnt[i], 1);
        atomicAdd(&cnt[j], 1);
    }
    __syncthreads();

    const int deg = (tid < N_NODES) ? cnt[tid] : 0;
    int x = deg;
    #pragma unroll
    for (int s = 1; s < 64; s <<= 1) {
        int t = __shfl_up(x, s, 64);
        if (lane >= s) x += t;
    }
    if (lane == 63) wsum[wid] = x;
    int dcap = deg > 63 ? 63 : deg;
    if (tid < N_NODES) atomicAdd(&dcur[dcap], 1);
    __syncthreads();

    int base = 0;
    for (int i = 0; i < wid; ++i) base += wsum[i];
    const int excl = base + x - deg;
    if (tid < N_NODES) { csr_off[tid] = excl; cursor[tid] = excl; }
    if (tid == 255)    { csr_off[N_NODES] = base + x; }

    if (tid < 64) {
        int h = dcur[63 - tid];
        int xs = h;
        #pragma unroll
        for (int s = 1; s < 64; s <<= 1) {
            int t = __shfl_up(xs, s, 64);
            if (lane >= s) xs += t;
        }
        __syncthreads();
        dcur[63 - tid] = xs - h;
    } else {
        __syncthreads();
    }
    __syncthreads();

    if (tid < N_NODES) {
        int p = atomicAdd(&dcur[dcap], 1);
        perm[p] = tid;
    }
    __syncthreads();

    for (int e = tid; e < N_EDGES; e += 256) {
        int i = edge_index[e];
        int j = edge_index[N_EDGES + e];
        int pi = atomicAdd(&cursor[i], 1);
        ent_edge[pi] = (unsigned)e;
        nbr_g[pi] = (unsigned char)j;
        int pj = atomicAdd(&cursor[j], 1);
        ent_edge[pj] = (unsigned)e;
        nbr_g[pj] = (unsigned char)i;
    }
}

// ---------------------------------------------------------------------------
// Kernel 2 (288 blocks): per-slot entry-ordered packed f16x2 weights.
// wtp[s][k] = pack(wr[s, edge(k)], wd[s, edge(k)]).
// ---------------------------------------------------------------------------
__global__ __launch_bounds__(256) void wperm_kernel(
    const unsigned* __restrict__ ent_edge,
    const float* __restrict__ w_react,
    const float* __restrict__ w_diff,
    unsigned* __restrict__ wtp)             // [N_SLOTS, WTP]
{
    const int s = blockIdx.x;
    const float* wrg = w_react + (size_t)s * N_EDGES;
    const float* wdg = w_diff  + (size_t)s * N_EDGES;
    unsigned* o = wtp + (size_t)s * WTP;
    for (int k = threadIdx.x; k < TOT_ENT; k += 256) {
        unsigned e = ent_edge[k];
        o[k] = pkrtz(wrg[e], wdg[e]);
    }
}

// ---------------------------------------------------------------------------
// Kernel 3 (1024 blocks): fused main. Block = sample; thread tid owns node
// perm[tid], ALL 24 channels. Per entry: 1 u8 + 1 b32 + 3 b128 LDS,
// 24 v_pk_fma_f16 (op_sel broadcast), 1 v_pk_add_f16 — no unpack/splat/
// indirection. x rows 48 B (stride 12 words -> 8 bank-start positions).
// LDS 27.2 KB; grid-capped 4 blocks/CU.
// ---------------------------------------------------------------------------
__global__ __launch_bounds__(256, 4) void rdgcn_main_kernel(
    const float* __restrict__ x_in,      // [B, 24, 207]
    const float* __restrict__ b_react,   // [N_SLOTS, N_NODES]
    const float* __restrict__ b_diff,    // [N_SLOTS, N_NODES]
    const float* __restrict__ w_self,    // [N_SLOTS, N_NODES]
    const int* __restrict__ ind,         // [B]
    const int* __restrict__ csr_off,     // [N_NODES + 1]
    const int* __restrict__ perm,        // [N_NODES]
    const unsigned char* __restrict__ nbr_g, // [WTP]
    const unsigned* __restrict__ wtp,    // [N_SLOTS, WTP]
    float* __restrict__ out)             // [B, 207, 24]
{
    __shared__ unsigned x_sh[N_NODES * NPK];    // 9936 B, 48-B rows
    __shared__ unsigned wt_sh[WTP];             // 13824 B
    __shared__ unsigned char nbr_sh[WTP];       // 3456 B   (total 27216 B)

    const int b   = blockIdx.x;
    const int tid = threadIdx.x;
    const int s   = ind[b];             // RESOLUTION == 1

    // Hoist per-thread scalars; latency hides under staging.
    int w = 0, beg = 0, end = 0;
    float br = 0.f, bd = 0.f, wsl = 0.f;
    if (tid < N_NODES) {
        w   = perm[tid];
        beg = csr_off[w];
        end = csr_off[w + 1];
        br  = b_react[s * N_NODES + w];
        bd  = b_diff [s * N_NODES + w];
        wsl = w_self [s * N_NODES + w];
    }

    // Stage packed weights (864 uint4, L2-hot) and neighbors (216 uint4).
    {
        const uint4* g = reinterpret_cast<const uint4*>(wtp + (size_t)s * WTP);
        uint4* d = reinterpret_cast<uint4*>(wt_sh);
        for (int k = tid; k < WTP / 4; k += 256) d[k] = g[k];
    }
    {
        const uint4* g = reinterpret_cast<const uint4*>(nbr_g);
        uint4* d = reinterpret_cast<uint4*>(nbr_sh);
        if (tid < WTP / 16) d[tid] = g[tid];
    }
    // Stage x: thread v gathers its node row (coalesced per l), packs 12
    // f16x2 words, writes 3 x b128 (48-B rows).
    const float* xg = x_in + (size_t)b * (L_DIM * N_NODES);
    if (tid < N_NODES) {
        float r[L_DIM];
        #pragma unroll
        for (int l = 0; l < L_DIM; ++l) r[l] = xg[l * N_NODES + tid];
        unsigned p[NPK];
        #pragma unroll
        for (int i = 0; i < NPK; ++i) p[i] = pkrtz(r[2*i], r[2*i+1]);
        uint4* dst = reinterpret_cast<uint4*>(&x_sh[tid * NPK]);
        dst[0] = make_uint4(p[0], p[1], p[2],  p[3]);
        dst[1] = make_uint4(p[4], p[5], p[6],  p[7]);
        dst[2] = make_uint4(p[8], p[9], p[10], p[11]);
    }
    __syncthreads();

    if (tid >= N_NODES) return;

    unsigned accr[NPK] = {0,0,0,0,0,0,0,0,0,0,0,0};   // f16x2 (reaction)
    unsigned accd[NPK] = {0,0,0,0,0,0,0,0,0,0,0,0};   // f16x2 (diffusion)
    unsigned sw = 0;                    // f16x2 (d_r, d_d) degree sums

    for (int k = beg; k < end; ++k) {
        const int nbr = nbr_sh[k];
        const unsigned wt = wt_sh[k];
        const uint4* xr = reinterpret_cast<const uint4*>(&x_sh[nbr * NPK]);
        const uint4 qa = xr[0], qb = xr[1], qc = xr[2];
        addw(sw, wt);
        fma_lo(accr[0],  wt, qa.x);   fma_hi(accd[0],  wt, qa.x);
        fma_lo(accr[1],  wt, qa.y);   fma_hi(accd[1],  wt, qa.y);
        fma_lo(accr[2],  wt, qa.z);   fma_hi(accd[2],  wt, qa.z);
        fma_lo(accr[3],  wt, qa.w);   fma_hi(accd[3],  wt, qa.w);
        fma_lo(accr[4],  wt, qb.x);   fma_hi(accd[4],  wt, qb.x);
        fma_lo(accr[5],  wt, qb.y);   fma_hi(accd[5],  wt, qb.y);
        fma_lo(accr[6],  wt, qb.z);   fma_hi(accd[6],  wt, qb.z);
        fma_lo(accr[7],  wt, qb.w);   fma_hi(accd[7],  wt, qb.w);
        fma_lo(accr[8],  wt, qc.x);   fma_hi(accd[8],  wt, qc.x);
        fma_lo(accr[9],  wt, qc.y);   fma_hi(accd[9],  wt, qc.y);
        fma_lo(accr[10], wt, qc.z);   fma_hi(accd[10], wt, qc.z);
        fma_lo(accr[11], wt, qc.w);   fma_hi(accd[11], wt, qc.w);
    }

    const f32x2 sw2 = h2f(sw);
    const float swr = sw2.x, swd = sw2.y;

    const uint4* xw = reinterpret_cast<const uint4*>(&x_sh[w * NPK]);
    const uint4 r0 = xw[0], r1 = xw[1], r2 = xw[2];
    const unsigned own[NPK] = { r0.x, r0.y, r0.z, r0.w,
                                r1.x, r1.y, r1.z, r1.w,
                                r2.x, r2.y, r2.z, r2.w };

    float o[L_DIM];
    #pragma unroll
    for (int i = 0; i < NPK; ++i) {
        const f32x2 xv = h2f(own[i]);
        const f32x2 ar = h2f(accr[i]);
        const f32x2 ad = h2f(accd[i]);
        {
            float re = fmaf(swr, xv.x,  ar.x) + br;
            float di = fmaf(swd, xv.x, -ad.x) + bd;
            o[2*i]   = fast_tanhf(re) + di + fmaf(xv.x, wsl, xv.x);
        }
        {
            float re = fmaf(swr, xv.y,  ar.y) + br;
            float di = fmaf(swd, xv.y, -ad.y) + bd;
            o[2*i+1] = fast_tanhf(re) + di + fmaf(xv.y, wsl, xv.y);
        }
    }
    float* op = out + (size_t)b * (N_NODES * L_DIM) + (size_t)w * L_DIM;
    reinterpret_cast<float4*>(op)[0] = make_float4(o[0],  o[1],  o[2],  o[3]);
    reinterpret_cast<float4*>(op)[1] = make_float4(o[4],  o[5],  o[6],  o[7]);
    reinterpret_cast<float4*>(op)[2] = make_float4(o[8],  o[9],  o[10], o[11]);
    reinterpret_cast<float4*>(op)[3] = make_float4(o[12], o[13], o[14], o[15]);
    reinterpret_cast<float4*>(op)[4] = make_float4(o[16], o[17], o[18], o[19]);
    reinterpret_cast<float4*>(op)[5] = make_float4(o[20], o[21], o[22], o[23]);
}

extern "C" void kernel_launch(void* const* d_in, const int* in_sizes, int n_in,
                              void* d_out, int out_size, void* d_ws, size_t ws_size,
                              hipStream_t stream) {
    const float* x_in     = (const float*)d_in[0];
    const float* w_react  = (const float*)d_in[1];
    const float* w_diff   = (const float*)d_in[2];
    const float* b_react  = (const float*)d_in[3];
    const float* b_diff   = (const float*)d_in[4];
    const float* w_self   = (const float*)d_in[5];
    const int*   ind      = (const int*)d_in[6];
    const int*   edge_idx = (const int*)d_in[7];
    float* out = (float*)d_out;

    // ws: csr_off | perm | ent_edge | nbr | wtp (288 x 3456 u32 = 3.98 MB)
    char* wp = (char*)d_ws;
    int* csr_off = (int*)wp;                 wp += 1024;
    int* perm = (int*)wp;                    wp += 1024;
    unsigned* ent_edge = (unsigned*)wp;      wp += WTP * sizeof(unsigned);
    unsigned char* nbr_g = (unsigned char*)wp; wp += (WTP + 256);
    wp = (char*)(((size_t)wp + 255) & ~(size_t)255);
    unsigned* wtp = (unsigned*)wp;

    build_csr_kernel<<<1, 256, 0, stream>>>(edge_idx, csr_off, perm,
                                            ent_edge, nbr_g);
    wperm_kernel<<<N_SLOTS, 256, 0, stream>>>(ent_edge, w_react, w_diff, wtp);

    const int B = in_sizes[6];   // 1024
    rdgcn_main_kernel<<<B, 256, 0, stream>>>(x_in, b_react, b_diff, w_self,
                                             ind, csr_off, perm, nbr_g,
                                             wtp, out);
}

// Round 11
// 30.390 us; speedup vs baseline: 1.4236x; 1.2672x over previous
//
#include <hip/hip_runtime.h>

#define N_NODES 207
#define N_EDGES 1722
#define N_SLOTS 288
#define L_DIM 24            // 2*12 feature channels
#define NPK 12              // f16x2 words per node row (24 ch, 48 B)
#define TOT_ENT (2 * N_EDGES)   // 3444

typedef float f32x2 __attribute__((ext_vector_type(2)));
typedef __fp16 h16x2 __attribute__((ext_vector_type(2)));

// pack 2 f32 -> f16x2 (v_cvt_pkrtz_f16_f32)
__device__ __forceinline__ unsigned pkrtz(float a, float b) {
    h16x2 h = __builtin_amdgcn_cvt_pkrtz(a, b);
    return __builtin_bit_cast(unsigned, h);
}
__device__ __forceinline__ f32x2 h2f(unsigned u) {
    h16x2 h = __builtin_bit_cast(h16x2, u);
    f32x2 r; r.x = (float)h.x; r.y = (float)h.y;
    return r;
}
// acc(f16x2) += {wr,wr} * x ; wr = lo16 of wt (op_sel lo-broadcast).
__device__ __forceinline__ void fma_lo(unsigned& acc, unsigned wt, unsigned x) {
    asm("v_pk_fma_f16 %0, %1, %2, %0 op_sel:[0,0,0] op_sel_hi:[0,1,1]"
        : "+v"(acc) : "v"(wt), "v"(x));
}
// acc(f16x2) += {wd,wd} * x ; wd = hi16 of wt.
__device__ __forceinline__ void fma_hi(unsigned& acc, unsigned wt, unsigned x) {
    asm("v_pk_fma_f16 %0, %1, %2, %0 op_sel:[1,0,0] op_sel_hi:[1,1,1]"
        : "+v"(acc) : "v"(wt), "v"(x));
}
// sw(f16x2) += {wr,wd}  (degree sums for both matrices in one op)
__device__ __forceinline__ void addw(unsigned& sw, unsigned wt) {
    asm("v_pk_add_f16 %0, %1, %0" : "+v"(sw) : "v"(wt));
}
// fast tanh: 1 - 2/(e^{2x}+1); both saturation limits exact.
__device__ __forceinline__ float fast_tanhf(float x) {
    float e2 = __expf(2.0f * x);
    return 1.0f - 2.0f * __builtin_amdgcn_rcpf(e2 + 1.0f);
}

// ---------------------------------------------------------------------------
// Kernel 1 (1 block): CSR incidence + degree-desc node permutation.
// entries[k] = nbr | (edge << 16), sentinel-padded for 1-deep prefetch.
// ---------------------------------------------------------------------------
__global__ __launch_bounds__(256) void build_csr_kernel(
    const int* __restrict__ edge_index,     // [2, N_EDGES]
    int* __restrict__ csr_off,              // [N_NODES + 1]
    unsigned int* __restrict__ entries,     // [TOT_ENT + 4]
    int* __restrict__ perm)                 // [N_NODES] degree-desc order
{
    __shared__ int cnt[N_NODES];
    __shared__ int cursor[N_NODES];
    __shared__ int wsum[4];
    __shared__ int dcur[64];
    const int tid  = threadIdx.x;
    const int lane = tid & 63;
    const int wid  = tid >> 6;

    if (tid < N_NODES) cnt[tid] = 0;
    if (tid < 64) dcur[tid] = 0;
    __syncthreads();

    for (int e = tid; e < N_EDGES; e += 256) {
        int i = edge_index[e];
        int j = edge_index[N_EDGES + e];
        atomicAdd(&cnt[i], 1);
        atomicAdd(&cnt[j], 1);
    }
    __syncthreads();

    const int deg = (tid < N_NODES) ? cnt[tid] : 0;
    int x = deg;
    #pragma unroll
    for (int s = 1; s < 64; s <<= 1) {
        int t = __shfl_up(x, s, 64);
        if (lane >= s) x += t;
    }
    if (lane == 63) wsum[wid] = x;
    int dcap = deg > 63 ? 63 : deg;
    if (tid < N_NODES) atomicAdd(&dcur[dcap], 1);
    __syncthreads();

    int base = 0;
    for (int i = 0; i < wid; ++i) base += wsum[i];
    const int excl = base + x - deg;
    if (tid < N_NODES) { csr_off[tid] = excl; cursor[tid] = excl; }
    if (tid == 255) {
        csr_off[N_NODES] = base + x;
        entries[TOT_ENT]     = 0u;
        entries[TOT_ENT + 1] = 0u;
    }

    if (tid < 64) {
        int h = dcur[63 - tid];
        int xs = h;
        #pragma unroll
        for (int s = 1; s < 64; s <<= 1) {
            int t = __shfl_up(xs, s, 64);
            if (lane >= s) xs += t;
        }
        __syncthreads();
        dcur[63 - tid] = xs - h;
    } else {
        __syncthreads();
    }
    __syncthreads();

    if (tid < N_NODES) {
        int p = atomicAdd(&dcur[dcap], 1);
        perm[p] = tid;
    }
    __syncthreads();

    for (int e = tid; e < N_EDGES; e += 256) {
        int i = edge_index[e];
        int j = edge_index[N_EDGES + e];
        int pi = atomicAdd(&cursor[i], 1);
        entries[pi] = (unsigned int)j | ((unsigned int)e << 16);
        int pj = atomicAdd(&cursor[j], 1);
        entries[pj] = (unsigned int)i | ((unsigned int)e << 16);
    }
}

// ---------------------------------------------------------------------------
// Kernel 2 (1024 blocks): fused main. Block = sample; thread tid owns node
// perm[tid], all 24 channels. R5 structure (no serial wperm prologue) +
// f16 op_sel compute diet: per entry 2 b32 + 3 b128 LDS reads,
// 24 v_pk_fma_f16 (op_sel broadcast), 1 v_pk_add_f16 — no unpack/splat.
// LDS 30.6 KB; grid-capped 4 blocks/CU.
// ---------------------------------------------------------------------------
__global__ __launch_bounds__(256, 4) void rdgcn_main_kernel(
    const float* __restrict__ x_in,      // [B, 24, 207]
    const float* __restrict__ w_react,   // [N_SLOTS, N_EDGES]
    const float* __restrict__ w_diff,    // [N_SLOTS, N_EDGES]
    const float* __restrict__ b_react,   // [N_SLOTS, N_NODES]
    const float* __restrict__ b_diff,    // [N_SLOTS, N_NODES]
    const float* __restrict__ w_self,    // [N_SLOTS, N_NODES]
    const int* __restrict__ ind,         // [B]
    const int* __restrict__ csr_off,     // [N_NODES + 1]
    const unsigned int* __restrict__ entries, // [TOT_ENT + 4]
    const int* __restrict__ perm,        // [N_NODES]
    float* __restrict__ out)             // [B, 207, 24]
{
    __shared__ unsigned x_sh[N_NODES * NPK];   // 9936 B, 48-B f16x2 rows
    __shared__ unsigned wt_sh[N_EDGES];        // 6888 B, f16x2 (wr, wd)
    __shared__ unsigned ent_sh[TOT_ENT + 4];   // 13792 B  (total 30616 B)

    const int b   = blockIdx.x;
    const int tid = threadIdx.x;
    const int s   = ind[b];             // RESOLUTION == 1

    // Hoist per-thread scalars; latency hides under staging.
    int w = 0, beg = 0, end = 0;
    float br = 0.f, bd = 0.f, wsl = 0.f;
    if (tid < N_NODES) {
        w   = perm[tid];
        beg = csr_off[w];
        end = csr_off[w + 1];
        br  = b_react[s * N_NODES + w];
        bd  = b_diff [s * N_NODES + w];
        wsl = w_self [s * N_NODES + w];
    }

    // Stage entries: uint4 coalesced (TOT_ENT = 3444 = 861*4) + sentinels.
    {
        const uint4* eg4 = reinterpret_cast<const uint4*>(entries);
        uint4* es4 = reinterpret_cast<uint4*>(ent_sh);
        for (int k = tid; k < TOT_ENT / 4; k += 256) es4[k] = eg4[k];
        if (tid == 0) { ent_sh[TOT_ENT] = 0u; ent_sh[TOT_ENT + 1] = 0u; }
    }
    // Stage x: thread v gathers its node row (coalesced per l), packs 12
    // f16x2 words, writes 3 x b128 (48-B rows).
    const float* xg = x_in + (size_t)b * (L_DIM * N_NODES);
    if (tid < N_NODES) {
        float r[L_DIM];
        #pragma unroll
        for (int l = 0; l < L_DIM; ++l) r[l] = xg[l * N_NODES + tid];
        unsigned p[NPK];
        #pragma unroll
        for (int i = 0; i < NPK; ++i) p[i] = pkrtz(r[2*i], r[2*i+1]);
        uint4* dst = reinterpret_cast<uint4*>(&x_sh[tid * NPK]);
        dst[0] = make_uint4(p[0], p[1], p[2],  p[3]);
        dst[1] = make_uint4(p[4], p[5], p[6],  p[7]);
        dst[2] = make_uint4(p[8], p[9], p[10], p[11]);
    }
    // Stage this slot's edge weights as packed f16x2 (coalesced reads).
    {
        const float* wrg = w_react + (size_t)s * N_EDGES;
        const float* wdg = w_diff  + (size_t)s * N_EDGES;
        for (int e = tid; e < N_EDGES; e += 256)
            wt_sh[e] = pkrtz(wrg[e], wdg[e]);
    }
    __syncthreads();

    if (tid >= N_NODES) return;

    unsigned accr[NPK] = {0,0,0,0,0,0,0,0,0,0,0,0};   // f16x2 (reaction)
    unsigned accd[NPK] = {0,0,0,0,0,0,0,0,0,0,0,0};   // f16x2 (diffusion)
    unsigned sw = 0;                    // f16x2 (d_r, d_d) degree sums

    unsigned en = ent_sh[beg];          // sentinel-safe
    for (int k = beg; k < end; ++k) {
        const unsigned en_nx = ent_sh[k + 1];   // 1-deep prefetch
        const int nbr = (int)(en & 0xffffu);
        const int e   = (int)(en >> 16);
        const unsigned wt = wt_sh[e];
        const uint4* xr = reinterpret_cast<const uint4*>(&x_sh[nbr * NPK]);
        const uint4 qa = xr[0], qb = xr[1], qc = xr[2];
        en = en_nx;
        addw(sw, wt);
        fma_lo(accr[0],  wt, qa.x);   fma_hi(accd[0],  wt, qa.x);
        fma_lo(accr[1],  wt, qa.y);   fma_hi(accd[1],  wt, qa.y);
        fma_lo(accr[2],  wt, qa.z);   fma_hi(accd[2],  wt, qa.z);
        fma_lo(accr[3],  wt, qa.w);   fma_hi(accd[3],  wt, qa.w);
        fma_lo(accr[4],  wt, qb.x);   fma_hi(accd[4],  wt, qb.x);
        fma_lo(accr[5],  wt, qb.y);   fma_hi(accd[5],  wt, qb.y);
        fma_lo(accr[6],  wt, qb.z);   fma_hi(accd[6],  wt, qb.z);
        fma_lo(accr[7],  wt, qb.w);   fma_hi(accd[7],  wt, qb.w);
        fma_lo(accr[8],  wt, qc.x);   fma_hi(accd[8],  wt, qc.x);
        fma_lo(accr[9],  wt, qc.y);   fma_hi(accd[9],  wt, qc.y);
        fma_lo(accr[10], wt, qc.z);   fma_hi(accd[10], wt, qc.z);
        fma_lo(accr[11], wt, qc.w);   fma_hi(accd[11], wt, qc.w);
    }

    const f32x2 sw2 = h2f(sw);
    const float swr = sw2.x, swd = sw2.y;

    const uint4* xw = reinterpret_cast<const uint4*>(&x_sh[w * NPK]);
    const uint4 r0 = xw[0], r1 = xw[1], r2 = xw[2];
    const unsigned own[NPK] = { r0.x, r0.y, r0.z, r0.w,
                                r1.x, r1.y, r1.z, r1.w,
                                r2.x, r2.y, r2.z, r2.w };

    float o[L_DIM];
    #pragma unroll
    for (int i = 0; i < NPK; ++i) {
        const f32x2 xv = h2f(own[i]);
        const f32x2 ar = h2f(accr[i]);
        const f32x2 ad = h2f(accd[i]);
        {
            float re = fmaf(swr, xv.x,  ar.x) + br;
            float di = fmaf(swd, xv.x, -ad.x) + bd;
            o[2*i]   = fast_tanhf(re) + di + fmaf(xv.x, wsl, xv.x);
        }
        {
            float re = fmaf(swr, xv.y,  ar.y) + br;
            float di = fmaf(swd, xv.y, -ad.y) + bd;
            o[2*i+1] = fast_tanhf(re) + di + fmaf(xv.y, wsl, xv.y);
        }
    }
    float* op = out + (size_t)b * (N_NODES * L_DIM) + (size_t)w * L_DIM;
    reinterpret_cast<float4*>(op)[0] = make_float4(o[0],  o[1],  o[2],  o[3]);
    reinterpret_cast<float4*>(op)[1] = make_float4(o[4],  o[5],  o[6],  o[7]);
    reinterpret_cast<float4*>(op)[2] = make_float4(o[8],  o[9],  o[10], o[11]);
    reinterpret_cast<float4*>(op)[3] = make_float4(o[12], o[13], o[14], o[15]);
    reinterpret_cast<float4*>(op)[4] = make_float4(o[16], o[17], o[18], o[19]);
    reinterpret_cast<float4*>(op)[5] = make_float4(o[20], o[21], o[22], o[23]);
}

extern "C" void kernel_launch(void* const* d_in, const int* in_sizes, int n_in,
                              void* d_out, int out_size, void* d_ws, size_t ws_size,
                              hipStream_t stream) {
    const float* x_in     = (const float*)d_in[0];
    const float* w_react  = (const float*)d_in[1];
    const float* w_diff   = (const float*)d_in[2];
    const float* b_react  = (const float*)d_in[3];
    const float* b_diff   = (const float*)d_in[4];
    const float* w_self   = (const float*)d_in[5];
    const int*   ind      = (const int*)d_in[6];
    const int*   edge_idx = (const int*)d_in[7];
    float* out = (float*)d_out;

    // ws layout: csr_off [208 ints] | entries [TOT_ENT+4 u32] | perm [256 ints]
    char* wp = (char*)d_ws;
    int* csr_off = (int*)wp;
    wp += (((size_t)(N_NODES + 1) * sizeof(int)) + 255) & ~(size_t)255;
    unsigned int* entries = (unsigned int*)wp;
    wp += (((size_t)(TOT_ENT + 4) * sizeof(unsigned int)) + 255) & ~(size_t)255;
    int* perm = (int*)wp;

    build_csr_kernel<<<1, 256, 0, stream>>>(edge_idx, csr_off, entries, perm);

    const int B = in_sizes[6];   // 1024
    rdgcn_main_kernel<<<B, 256, 0, stream>>>(x_in, w_react, w_diff,
                                             b_react, b_diff, w_self,
                                             ind, csr_off, entries, perm, out);
}

// Round 12
// 27.036 us; speedup vs baseline: 1.6002x; 1.1240x over previous
//
#include <hip/hip_runtime.h>

#define N_NODES 207
#define N_EDGES 1722
#define N_SLOTS 288
#define L_DIM 24            // 2*12 feature channels
#define NPK 12              // f16x2 words per node row (24 ch, 48 B)
#define TOT_ENT (2 * N_EDGES)   // 3444

typedef float f32x2 __attribute__((ext_vector_type(2)));
typedef __fp16 h16x2 __attribute__((ext_vector_type(2)));

// pack 2 f32 -> f16x2 (v_cvt_pkrtz_f16_f32)
__device__ __forceinline__ unsigned pkrtz(float a, float b) {
    h16x2 h = __builtin_amdgcn_cvt_pkrtz(a, b);
    return __builtin_bit_cast(unsigned, h);
}
__device__ __forceinline__ f32x2 h2f(unsigned u) {
    h16x2 h = __builtin_bit_cast(h16x2, u);
    f32x2 r; r.x = (float)h.x; r.y = (float)h.y;
    return r;
}
// acc(f16x2) += {wr,wr} * x ; wr = lo16 of wt (op_sel lo-broadcast).
__device__ __forceinline__ void fma_lo(unsigned& acc, unsigned wt, unsigned x) {
    asm("v_pk_fma_f16 %0, %1, %2, %0 op_sel:[0,0,0] op_sel_hi:[0,1,1]"
        : "+v"(acc) : "v"(wt), "v"(x));
}
// acc(f16x2) += {wd,wd} * x ; wd = hi16 of wt.
__device__ __forceinline__ void fma_hi(unsigned& acc, unsigned wt, unsigned x) {
    asm("v_pk_fma_f16 %0, %1, %2, %0 op_sel:[1,0,0] op_sel_hi:[1,1,1]"
        : "+v"(acc) : "v"(wt), "v"(x));
}
// sw(f16x2) += {wr,wd}  (degree sums for both matrices in one op)
__device__ __forceinline__ void addw(unsigned& sw, unsigned wt) {
    asm("v_pk_add_f16 %0, %1, %0" : "+v"(sw) : "v"(wt));
}
// fast tanh: 1 - 2/(e^{2x}+1); both saturation limits exact.
__device__ __forceinline__ float fast_tanhf(float x) {
    float e2 = __expf(2.0f * x);
    return 1.0f - 2.0f * __builtin_amdgcn_rcpf(e2 + 1.0f);
}

// ---------------------------------------------------------------------------
// Single fused kernel (1024 blocks). Each block:
//   1. builds CSR incidence + degree-desc perm in LDS from edge_index
//      (edges cached in registers between count & placement passes);
//   2. stages x (f16x2 48-B rows) + this slot's weights (f16x2);
//   3. per-thread gather loop (f16 op_sel pk_fma pipeline);
//   4. epilogue (f32 tanh/diffusion/self-loop) + float4 stores.
// Build scratch aliases the x_sh region; consumed into regs before staging.
// Removes the serial build_csr kernel + second launch from the critical path.
// ---------------------------------------------------------------------------
__global__ __launch_bounds__(256, 4) void rdgcn_fused_kernel(
    const float* __restrict__ x_in,      // [B, 24, 207]
    const float* __restrict__ w_react,   // [N_SLOTS, N_EDGES]
    const float* __restrict__ w_diff,    // [N_SLOTS, N_EDGES]
    const float* __restrict__ b_react,   // [N_SLOTS, N_NODES]
    const float* __restrict__ b_diff,    // [N_SLOTS, N_NODES]
    const float* __restrict__ w_self,    // [N_SLOTS, N_NODES]
    const int* __restrict__ ind,         // [B]
    const int* __restrict__ edge_index,  // [2, N_EDGES]
    float* __restrict__ out)             // [B, 207, 24]
{
    __shared__ unsigned x_sh[N_NODES * NPK];   // 9936 B (build scratch aliases)
    __shared__ unsigned wt_sh[N_EDGES];        // 6888 B
    __shared__ unsigned ent_sh[TOT_ENT + 4];   // 13792 B  (total 30616 B)

    const int b    = blockIdx.x;
    const int tid  = threadIdx.x;
    const int lane = tid & 63;
    const int wid  = tid >> 6;
    const int s    = ind[b];            // RESOLUTION == 1

    // ---- build scratch aliased inside x_sh (901 ints < 2484 available) ----
    int* cnt_s  = (int*)x_sh;           // [208]
    int* cur_s  = cnt_s + 208;          // [208]
    int* off_s  = cur_s + 208;          // [209]
    int* perm_s = off_s + 209;          // [208]
    int* dcur_s = perm_s + 208;         // [64]
    int* wsum_s = dcur_s + 64;          // [4]

    if (tid < 208) cnt_s[tid] = 0;
    if (tid < 64)  dcur_s[tid] = 0;
    __syncthreads();

    // pass 1: degree count; cache edge endpoints in registers (<=7 per thread)
    int ei[7], ej[7];
    int ne = 0;
    for (int e = tid; e < N_EDGES; e += 256) {
        int i = edge_index[e];
        int j = edge_index[N_EDGES + e];
        ei[ne] = i; ej[ne] = j; ++ne;
        atomicAdd(&cnt_s[i], 1);
        atomicAdd(&cnt_s[j], 1);
    }
    __syncthreads();

    // exclusive scan of degrees (shfl within wave + cross-wave wsum)
    const int deg = (tid < N_NODES) ? cnt_s[tid] : 0;
    int xs = deg;
    #pragma unroll
    for (int sft = 1; sft < 64; sft <<= 1) {
        int t = __shfl_up(xs, sft, 64);
        if (lane >= sft) xs += t;
    }
    if (lane == 63) wsum_s[wid] = xs;
    const int dcap = deg > 63 ? 63 : deg;
    if (tid < N_NODES) atomicAdd(&dcur_s[dcap], 1);
    __syncthreads();

    int base = 0;
    for (int i = 0; i < wid; ++i) base += wsum_s[i];
    const int excl = base + xs - deg;
    if (tid < N_NODES) { off_s[tid] = excl; cur_s[tid] = excl; }
    if (tid == 255)    off_s[N_NODES] = base + xs;

    // descending-degree exclusive offsets for counting sort
    if (tid < 64) {
        int h = dcur_s[63 - tid];
        int ys = h;
        #pragma unroll
        for (int sft = 1; sft < 64; sft <<= 1) {
            int t = __shfl_up(ys, sft, 64);
            if (lane >= sft) ys += t;
        }
        __syncthreads();                 // all reads of dcur done
        dcur_s[63 - tid] = ys - h;
    } else {
        __syncthreads();
    }
    __syncthreads();

    if (tid < N_NODES) {
        int p = atomicAdd(&dcur_s[dcap], 1);
        perm_s[p] = tid;
    }
    // pass 2: entry placement straight from registers (no edge re-read)
    for (int q = 0; q < ne; ++q) {
        const int i = ei[q], j = ej[q];
        const int e = tid + q * 256;
        int pi = atomicAdd(&cur_s[i], 1);
        ent_sh[pi] = (unsigned)j | ((unsigned)e << 16);
        int pj = atomicAdd(&cur_s[j], 1);
        ent_sh[pj] = (unsigned)i | ((unsigned)e << 16);
    }
    if (tid == 0) { ent_sh[TOT_ENT] = 0u; ent_sh[TOT_ENT + 1] = 0u; }
    __syncthreads();

    // consume scratch into registers before staging overwrites it
    int w = 0, beg = 0, end = 0;
    if (tid < N_NODES) {
        w   = perm_s[tid];
        beg = off_s[w];
        end = off_s[w + 1];
    }
    __syncthreads();   // scratch reads complete before x_sh is overwritten

    float br = 0.f, bd = 0.f, wsl = 0.f;
    if (tid < N_NODES) {
        br  = b_react[s * N_NODES + w];
        bd  = b_diff [s * N_NODES + w];
        wsl = w_self [s * N_NODES + w];
    }
    // stage x: thread v gathers its node row (coalesced per l), packs 12
    // f16x2 words, writes 3 x b128 (48-B rows).
    const float* xg = x_in + (size_t)b * (L_DIM * N_NODES);
    if (tid < N_NODES) {
        float r[L_DIM];
        #pragma unroll
        for (int l = 0; l < L_DIM; ++l) r[l] = xg[l * N_NODES + tid];
        unsigned p[NPK];
        #pragma unroll
        for (int i = 0; i < NPK; ++i) p[i] = pkrtz(r[2*i], r[2*i+1]);
        uint4* dst = reinterpret_cast<uint4*>(&x_sh[tid * NPK]);
        dst[0] = make_uint4(p[0], p[1], p[2],  p[3]);
        dst[1] = make_uint4(p[4], p[5], p[6],  p[7]);
        dst[2] = make_uint4(p[8], p[9], p[10], p[11]);
    }
    // stage this slot's edge weights as packed f16x2 (coalesced reads)
    {
        const float* wrg = w_react + (size_t)s * N_EDGES;
        const float* wdg = w_diff  + (size_t)s * N_EDGES;
        for (int e = tid; e < N_EDGES; e += 256)
            wt_sh[e] = pkrtz(wrg[e], wdg[e]);
    }
    __syncthreads();

    if (tid >= N_NODES) return;

    unsigned accr[NPK] = {0,0,0,0,0,0,0,0,0,0,0,0};   // f16x2 (reaction)
    unsigned accd[NPK] = {0,0,0,0,0,0,0,0,0,0,0,0};   // f16x2 (diffusion)
    unsigned sw = 0;                    // f16x2 (d_r, d_d) degree sums

    unsigned en = ent_sh[beg];          // sentinel-safe
    for (int k = beg; k < end; ++k) {
        const unsigned en_nx = ent_sh[k + 1];   // 1-deep prefetch
        const int nbr = (int)(en & 0xffffu);
        const int e   = (int)(en >> 16);
        const unsigned wt = wt_sh[e];
        const uint4* xr = reinterpret_cast<const uint4*>(&x_sh[nbr * NPK]);
        const uint4 qa = xr[0], qb = xr[1], qc = xr[2];
        en = en_nx;
        addw(sw, wt);
        fma_lo(accr[0],  wt, qa.x);   fma_hi(accd[0],  wt, qa.x);
        fma_lo(accr[1],  wt, qa.y);   fma_hi(accd[1],  wt, qa.y);
        fma_lo(accr[2],  wt, qa.z);   fma_hi(accd[2],  wt, qa.z);
        fma_lo(accr[3],  wt, qa.w);   fma_hi(accd[3],  wt, qa.w);
        fma_lo(accr[4],  wt, qb.x);   fma_hi(accd[4],  wt, qb.x);
        fma_lo(accr[5],  wt, qb.y);   fma_hi(accd[5],  wt, qb.y);
        fma_lo(accr[6],  wt, qb.z);   fma_hi(accd[6],  wt, qb.z);
        fma_lo(accr[7],  wt, qb.w);   fma_hi(accd[7],  wt, qb.w);
        fma_lo(accr[8],  wt, qc.x);   fma_hi(accd[8],  wt, qc.x);
        fma_lo(accr[9],  wt, qc.y);   fma_hi(accd[9],  wt, qc.y);
        fma_lo(accr[10], wt, qc.z);   fma_hi(accd[10], wt, qc.z);
        fma_lo(accr[11], wt, qc.w);   fma_hi(accd[11], wt, qc.w);
    }

    const f32x2 sw2 = h2f(sw);
    const float swr = sw2.x, swd = sw2.y;

    const uint4* xw = reinterpret_cast<const uint4*>(&x_sh[w * NPK]);
    const uint4 r0 = xw[0], r1 = xw[1], r2 = xw[2];
    const unsigned own[NPK] = { r0.x, r0.y, r0.z, r0.w,
                                r1.x, r1.y, r1.z, r1.w,
                                r2.x, r2.y, r2.z, r2.w };

    float o[L_DIM];
    #pragma unroll
    for (int i = 0; i < NPK; ++i) {
        const f32x2 xv = h2f(own[i]);
        const f32x2 ar = h2f(accr[i]);
        const f32x2 ad = h2f(accd[i]);
        {
            float re = fmaf(swr, xv.x,  ar.x) + br;
            float di = fmaf(swd, xv.x, -ad.x) + bd;
            o[2*i]   = fast_tanhf(re) + di + fmaf(xv.x, wsl, xv.x);
        }
        {
            float re = fmaf(swr, xv.y,  ar.y) + br;
            float di = fmaf(swd, xv.y, -ad.y) + bd;
            o[2*i+1] = fast_tanhf(re) + di + fmaf(xv.y, wsl, xv.y);
        }
    }
    float* op = out + (size_t)b * (N_NODES * L_DIM) + (size_t)w * L_DIM;
    reinterpret_cast<float4*>(op)[0] = make_float4(o[0],  o[1],  o[2],  o[3]);
    reinterpret_cast<float4*>(op)[1] = make_float4(o[4],  o[5],  o[6],  o[7]);
    reinterpret_cast<float4*>(op)[2] = make_float4(o[8],  o[9],  o[10], o[11]);
    reinterpret_cast<float4*>(op)[3] = make_float4(o[12], o[13], o[14], o[15]);
    reinterpret_cast<float4*>(op)[4] = make_float4(o[16], o[17], o[18], o[19]);
    reinterpret_cast<float4*>(op)[5] = make_float4(o[20], o[21], o[22], o[23]);
}

extern "C" void kernel_launch(void* const* d_in, const int* in_sizes, int n_in,
                              void* d_out, int out_size, void* d_ws, size_t ws_size,
                              hipStream_t stream) {
    const float* x_in     = (const float*)d_in[0];
    const float* w_react  = (const float*)d_in[1];
    const float* w_diff   = (const float*)d_in[2];
    const float* b_react  = (const float*)d_in[3];
    const float* b_diff   = (const float*)d_in[4];
    const float* w_self   = (const float*)d_in[5];
    const int*   ind      = (const int*)d_in[6];
    const int*   edge_idx = (const int*)d_in[7];
    float* out = (float*)d_out;

    const int B = in_sizes[6];   // 1024
    rdgcn_fused_kernel<<<B, 256, 0, stream>>>(x_in, w_react, w_diff,
                                              b_react, b_diff, w_self,
                                              ind, edge_idx, out);
}

// Round 13
// 25.576 us; speedup vs baseline: 1.6915x; 1.0571x over previous
//
#include <hip/hip_runtime.h>

#define N_NODES 207
#define N_EDGES 1722
#define N_SLOTS 288
#define L_DIM 24            // 2*12 feature channels
#define NPK 12              // f16x2 words per node row (24 ch, 48 B)
#define TOT_ENT (2 * N_EDGES)   // 3444
#define THREADS 512         // 2 samples per block, 256 threads each

typedef float f32x2 __attribute__((ext_vector_type(2)));
typedef __fp16 h16x2 __attribute__((ext_vector_type(2)));

// pack 2 f32 -> f16x2 (v_cvt_pkrtz_f16_f32)
__device__ __forceinline__ unsigned pkrtz(float a, float b) {
    h16x2 h = __builtin_amdgcn_cvt_pkrtz(a, b);
    return __builtin_bit_cast(unsigned, h);
}
__device__ __forceinline__ f32x2 h2f(unsigned u) {
    h16x2 h = __builtin_bit_cast(h16x2, u);
    f32x2 r; r.x = (float)h.x; r.y = (float)h.y;
    return r;
}
// acc(f16x2) += {wr,wr} * x ; wr = lo16 of wt (op_sel lo-broadcast).
__device__ __forceinline__ void fma_lo(unsigned& acc, unsigned wt, unsigned x) {
    asm("v_pk_fma_f16 %0, %1, %2, %0 op_sel:[0,0,0] op_sel_hi:[0,1,1]"
        : "+v"(acc) : "v"(wt), "v"(x));
}
// acc(f16x2) += {wd,wd} * x ; wd = hi16 of wt.
__device__ __forceinline__ void fma_hi(unsigned& acc, unsigned wt, unsigned x) {
    asm("v_pk_fma_f16 %0, %1, %2, %0 op_sel:[1,0,0] op_sel_hi:[1,1,1]"
        : "+v"(acc) : "v"(wt), "v"(x));
}
// sw(f16x2) += {wr,wd}  (degree sums for both matrices in one op)
__device__ __forceinline__ void addw(unsigned& sw, unsigned wt) {
    asm("v_pk_add_f16 %0, %1, %0" : "+v"(sw) : "v"(wt));
}
// fast tanh: 1 - 2/(e^{2x}+1); both saturation limits exact.
__device__ __forceinline__ float fast_tanhf(float x) {
    float e2 = __expf(2.0f * x);
    return 1.0f - 2.0f * __builtin_amdgcn_rcpf(e2 + 1.0f);
}

// ---------------------------------------------------------------------------
// Single fused kernel, 512 blocks x 512 threads. Each block handles TWO
// samples (waves 0-3 -> sample A, waves 4-7 -> sample B) sharing ONE CSR
// build + entry table (halves build atomics/scans/edge reads per sample).
// x global loads are issued at kernel top into registers so their HBM
// latency hides under the build. Build scratch aliases the wt region
// (written only after scratch is consumed); x_sh is never aliased.
// ---------------------------------------------------------------------------
__global__ __launch_bounds__(THREADS, 4) void rdgcn_fused_kernel(
    const float* __restrict__ x_in,      // [B, 24, 207]
    const float* __restrict__ w_react,   // [N_SLOTS, N_EDGES]
    const float* __restrict__ w_diff,    // [N_SLOTS, N_EDGES]
    const float* __restrict__ b_react,   // [N_SLOTS, N_NODES]
    const float* __restrict__ b_diff,    // [N_SLOTS, N_NODES]
    const float* __restrict__ w_self,    // [N_SLOTS, N_NODES]
    const int* __restrict__ ind,         // [B]
    const int* __restrict__ edge_index,  // [2, N_EDGES]
    float* __restrict__ out)             // [B, 207, 24]
{
    __shared__ unsigned x_sh[2][N_NODES * NPK];   // 19872 B
    __shared__ unsigned wt_sh[2][N_EDGES];        // 13776 B (scratch aliases)
    __shared__ unsigned ent_sh[TOT_ENT + 4];      // 13792 B  (total 47440 B)

    const int tid  = threadIdx.x;
    const int h    = tid >> 8;          // sample half within block
    const int htid = tid & 255;         // thread id within half
    const int lane = tid & 63;
    const int wid  = tid >> 6;
    const int b    = blockIdx.x * 2 + h;
    const int s    = ind[b];            // RESOLUTION == 1

    // ---- issue x loads FIRST: HBM latency hides under the build ----
    float r[L_DIM];
    if (htid < N_NODES) {
        const float* xg = x_in + (size_t)b * (L_DIM * N_NODES);
        #pragma unroll
        for (int l = 0; l < L_DIM; ++l) r[l] = xg[l * N_NODES + htid];
    }

    // ---- build scratch aliased over wt_sh (901 ints < 3444 available) ----
    int* cnt_s  = (int*)wt_sh;          // [208]
    int* cur_s  = cnt_s + 208;          // [208]
    int* off_s  = cur_s + 208;          // [209]
    int* perm_s = off_s + 209;          // [208]
    int* dcur_s = perm_s + 208;         // [64]
    int* wsum_s = dcur_s + 64;          // [4]

    if (tid < 208) cnt_s[tid] = 0;
    if (tid < 64)  dcur_s[tid] = 0;
    __syncthreads();

    // pass 1: degree count; cache edge endpoints in registers (<=4/thread)
    int ei[4], ej[4];
    int ne = 0;
    for (int e = tid; e < N_EDGES; e += THREADS) {
        int i = edge_index[e];
        int j = edge_index[N_EDGES + e];
        ei[ne] = i; ej[ne] = j; ++ne;
        atomicAdd(&cnt_s[i], 1);
        atomicAdd(&cnt_s[j], 1);
    }
    __syncthreads();

    // exclusive scan of degrees over slots 0..255 (waves 0-3 only; whole
    // waves uniformly take the branch, so shfl is safe)
    const int deg  = (tid < N_NODES) ? cnt_s[tid] : 0;
    const int dcap = deg > 63 ? 63 : deg;
    int xs = deg;
    if (tid < 256) {
        #pragma unroll
        for (int sft = 1; sft < 64; sft <<= 1) {
            int t = __shfl_up(xs, sft, 64);
            if (lane >= sft) xs += t;
        }
        if (lane == 63) wsum_s[wid] = xs;
    }
    if (tid < N_NODES) atomicAdd(&dcur_s[dcap], 1);
    __syncthreads();

    int base = 0;
    if (tid < 256) { for (int i = 0; i < wid; ++i) base += wsum_s[i]; }
    const int excl = base + xs - deg;
    if (tid < N_NODES) { off_s[tid] = excl; cur_s[tid] = excl; }
    if (tid == 255)    off_s[N_NODES] = base + xs;

    // descending-degree exclusive offsets for the counting sort
    if (tid < 64) {
        int hg = dcur_s[63 - tid];
        int ys = hg;
        #pragma unroll
        for (int sft = 1; sft < 64; sft <<= 1) {
            int t = __shfl_up(ys, sft, 64);
            if (lane >= sft) ys += t;
        }
        __syncthreads();                 // all reads of dcur done
        dcur_s[63 - tid] = ys - hg;
    } else {
        __syncthreads();
    }
    __syncthreads();

    if (tid < N_NODES) {
        int p = atomicAdd(&dcur_s[dcap], 1);
        perm_s[p] = tid;
    }
    // pass 2: entry placement straight from registers
    for (int q = 0; q < ne; ++q) {
        const int e = tid + q * THREADS;
        int pi = atomicAdd(&cur_s[ei[q]], 1);
        ent_sh[pi] = (unsigned)ej[q] | ((unsigned)e << 16);
        int pj = atomicAdd(&cur_s[ej[q]], 1);
        ent_sh[pj] = (unsigned)ei[q] | ((unsigned)e << 16);
    }
    if (tid == 0) { ent_sh[TOT_ENT] = 0u; ent_sh[TOT_ENT + 1] = 0u; }
    __syncthreads();

    // consume scratch into registers before wt staging overwrites it
    int w = 0, beg = 0, end = 0;
    if (htid < N_NODES) {
        w   = perm_s[htid];
        beg = off_s[w];
        end = off_s[w + 1];
    }
    __syncthreads();   // scratch reads complete; wt_sh region free

    float br = 0.f, bd = 0.f, wsl = 0.f;
    if (htid < N_NODES) {
        br  = b_react[s * N_NODES + w];
        bd  = b_diff [s * N_NODES + w];
        wsl = w_self [s * N_NODES + w];
        // pack the (long-arrived) x row and write 3 x b128
        unsigned p[NPK];
        #pragma unroll
        for (int i = 0; i < NPK; ++i) p[i] = pkrtz(r[2*i], r[2*i+1]);
        uint4* dst = reinterpret_cast<uint4*>(&x_sh[h][htid * NPK]);
        dst[0] = make_uint4(p[0], p[1], p[2],  p[3]);
        dst[1] = make_uint4(p[4], p[5], p[6],  p[7]);
        dst[2] = make_uint4(p[8], p[9], p[10], p[11]);
    }
    // stage this half's slot weights as packed f16x2 (coalesced reads)
    {
        const float* wrg = w_react + (size_t)s * N_EDGES;
        const float* wdg = w_diff  + (size_t)s * N_EDGES;
        for (int e = htid; e < N_EDGES; e += 256)
            wt_sh[h][e] = pkrtz(wrg[e], wdg[e]);
    }
    __syncthreads();

    if (htid >= N_NODES) return;

    unsigned accr[NPK] = {0,0,0,0,0,0,0,0,0,0,0,0};   // f16x2 (reaction)
    unsigned accd[NPK] = {0,0,0,0,0,0,0,0,0,0,0,0};   // f16x2 (diffusion)
    unsigned sw = 0;                    // f16x2 (d_r, d_d) degree sums

    const unsigned* wth = wt_sh[h];
    const unsigned* xsh = x_sh[h];
    unsigned en = ent_sh[beg];          // sentinel-safe
    for (int k = beg; k < end; ++k) {
        const unsigned en_nx = ent_sh[k + 1];   // 1-deep prefetch
        const int nbr = (int)(en & 0xffffu);
        const int e   = (int)(en >> 16);
        const unsigned wt = wth[e];
        const uint4* xr = reinterpret_cast<const uint4*>(&xsh[nbr * NPK]);
        const uint4 qa = xr[0], qb = xr[1], qc = xr[2];
        en = en_nx;
        addw(sw, wt);
        fma_lo(accr[0],  wt, qa.x);   fma_hi(accd[0],  wt, qa.x);
        fma_lo(accr[1],  wt, qa.y);   fma_hi(accd[1],  wt, qa.y);
        fma_lo(accr[2],  wt, qa.z);   fma_hi(accd[2],  wt, qa.z);
        fma_lo(accr[3],  wt, qa.w);   fma_hi(accd[3],  wt, qa.w);
        fma_lo(accr[4],  wt, qb.x);   fma_hi(accd[4],  wt, qb.x);
        fma_lo(accr[5],  wt, qb.y);   fma_hi(accd[5],  wt, qb.y);
        fma_lo(accr[6],  wt, qb.z);   fma_hi(accd[6],  wt, qb.z);
        fma_lo(accr[7],  wt, qb.w);   fma_hi(accd[7],  wt, qb.w);
        fma_lo(accr[8],  wt, qc.x);   fma_hi(accd[8],  wt, qc.x);
        fma_lo(accr[9],  wt, qc.y);   fma_hi(accd[9],  wt, qc.y);
        fma_lo(accr[10], wt, qc.z);   fma_hi(accd[10], wt, qc.z);
        fma_lo(accr[11], wt, qc.w);   fma_hi(accd[11], wt, qc.w);
    }

    const f32x2 sw2 = h2f(sw);
    const float swr = sw2.x, swd = sw2.y;

    const uint4* xw = reinterpret_cast<const uint4*>(&xsh[w * NPK]);
    const uint4 r0 = xw[0], r1 = xw[1], r2 = xw[2];
    const unsigned own[NPK] = { r0.x, r0.y, r0.z, r0.w,
                                r1.x, r1.y, r1.z, r1.w,
                                r2.x, r2.y, r2.z, r2.w };

    float o[L_DIM];
    #pragma unroll
    for (int i = 0; i < NPK; ++i) {
        const f32x2 xv = h2f(own[i]);
        const f32x2 ar = h2f(accr[i]);
        const f32x2 ad = h2f(accd[i]);
        {
            float re = fmaf(swr, xv.x,  ar.x) + br;
            float di = fmaf(swd, xv.x, -ad.x) + bd;
            o[2*i]   = fast_tanhf(re) + di + fmaf(xv.x, wsl, xv.x);
        }
        {
            float re = fmaf(swr, xv.y,  ar.y) + br;
            float di = fmaf(swd, xv.y, -ad.y) + bd;
            o[2*i+1] = fast_tanhf(re) + di + fmaf(xv.y, wsl, xv.y);
        }
    }
    float* op = out + (size_t)b * (N_NODES * L_DIM) + (size_t)w * L_DIM;
    reinterpret_cast<float4*>(op)[0] = make_float4(o[0],  o[1],  o[2],  o[3]);
    reinterpret_cast<float4*>(op)[1] = make_float4(o[4],  o[5],  o[6],  o[7]);
    reinterpret_cast<float4*>(op)[2] = make_float4(o[8],  o[9],  o[10], o[11]);
    reinterpret_cast<float4*>(op)[3] = make_float4(o[12], o[13], o[14], o[15]);
    reinterpret_cast<float4*>(op)[4] = make_float4(o[16], o[17], o[18], o[19]);
    reinterpret_cast<float4*>(op)[5] = make_float4(o[20], o[21], o[22], o[23]);
}

extern "C" void kernel_launch(void* const* d_in, const int* in_sizes, int n_in,
                              void* d_out, int out_size, void* d_ws, size_t ws_size,
                              hipStream_t stream) {
    const float* x_in     = (const float*)d_in[0];
    const float* w_react  = (const float*)d_in[1];
    const float* w_diff   = (const float*)d_in[2];
    const float* b_react  = (const float*)d_in[3];
    const float* b_diff   = (const float*)d_in[4];
    const float* w_self   = (const float*)d_in[5];
    const int*   ind      = (const int*)d_in[6];
    const int*   edge_idx = (const int*)d_in[7];
    float* out = (float*)d_out;

    const int B = in_sizes[6];   // 1024
    rdgcn_fused_kernel<<<B / 2, THREADS, 0, stream>>>(x_in, w_react, w_diff,
                                                      b_react, b_diff, w_self,
                                                      ind, edge_idx, out);
}